// Round 14
// baseline (43.192 us; speedup 1.0000x reference)
//
#include <hip/hip_runtime.h>
#include <stdint.h>

// SKA: out[n, g*CW+cw, h, w] = sum_{a,b in 0..2} x[n, g*CW+cw, h+a-1, w+b-1] * w[n, cw, a*3+b, h, w]
// x: (8, 256, 96, 96) f32 ; w: (8, 32, 9, 96, 96) f32 ; out: (8, 256, 96, 96) f32
// Round 13: R12's request reduction on the PROVEN R10/R11 single-drain
// skeleton (R12's counted-vmcnt ladder aborted; manual vmcnt bookkeeping
// fights compiler-inserted waits when asm + IR loads interleave).
//  - Wave = 2 rows x 32 lanes; each wave loads only rows ho-1 / ho+1 per
//    group (16 asm-pinned dwordx4, g-outer for 1.5KB DRAM clusters); the
//    middle row ho comes from the other half-wave via shfl(X, lane^32),
//    computed BEFORE any divergent region. x requests 24 -> 16 per wave.
//  - Single s_waitcnt vmcnt(0) + sched_barrier (rule #18), as in R10/R11.
//  - Plain stores (R11 win), XCD-bijective swizzle.

#define N_  8
#define C_  256
#define H_  96
#define W_  96
#define CW_ 32
#define G_  8
#define PL_ (H_ * W_)  // 9216

typedef float f32x4 __attribute__((ext_vector_type(4)));

// order-pinned 16B global load (compiler cannot sink/reorder volatile asm)
#define GLD(dst, addr) \
    asm volatile("global_load_dwordx4 %0, %1, off" : "=v"(dst) : "v"(addr))

__global__ __launch_bounds__(256) void SKA_kernel(const float* __restrict__ x,
                                                  const float* __restrict__ wgt,
                                                  float* __restrict__ out) {
    const int tid  = threadIdx.x;
    const int lane = tid & 63;
    const int widx = lane & 31;   // 0..31, 24 active
    const int half = lane >> 5;   // 0 -> row hb, 1 -> row hb+1
    const int wid  = tid >> 6;    // wave 0..3

    // XCD-bijective swizzle: 3072 blocks = 8 XCDs x 384; each XCD owns one image n.
    const int b  = blockIdx.x;
    const int lb = (b & 7) * 384 + (b >> 3);
    const int ht = lb % 12;
    const int t1 = lb / 12;       // 0..255
    const int cw = t1 % CW_;
    const int n  = t1 / CW_;      // 0..7
    const int ho = ht * 8 + 2 * wid + half;  // my output row
    const int w0 = widx * 4;

    if (widx >= 24) return;

    // ---- 9 per-pixel kernel taps ----
    const float* wb = wgt + (size_t)(((n * CW_ + cw) * 9) * H_ + ho) * W_ + w0;
    f32x4 wv[9];
#pragma unroll
    for (int k = 0; k < 9; ++k)
        wv[k] = *reinterpret_cast<const f32x4*>(wb + k * PL_);
    __builtin_amdgcn_sched_barrier(0);  // pin wv issue before the x batch

    // ---- 16 order-pinned x loads: rows ho-1 (A) and ho+1 (B) per group.
    // Per group the wave's two halves cover rows hb-1..hb+2 contiguously. ----
    const float* xb = x + (size_t)((n * C_ + cw) * PL_) + w0;
    const int rA = (ho - 1 < 0) ? 0 : ho - 1;        // clamp; masked at compute
    const int rB = (ho + 1 >= H_) ? H_ - 1 : ho + 1;

    f32x4 xa[G_], xbv[G_];
#pragma unroll
    for (int g = 0; g < G_; ++g) {
        const float* xg = xb + (size_t)(g * CW_) * PL_;
        GLD(xa[g],  xg + rA * W_);
        GLD(xbv[g], xg + rB * W_);
    }

    // single drain of pinned loads; fence consumer hoisting (rule #18)
    asm volatile("s_waitcnt vmcnt(0)" ::: "memory");
    __builtin_amdgcn_sched_barrier(0);

    // ---- recover middle rows via cross-half exchange (uniform, pre-divergence):
    // other half's A (for half0) or B (for half1) is exactly my row ho.
    f32x4 mid[G_];
#pragma unroll
    for (int g = 0; g < G_; ++g) {
        const f32x4 X = half ? xa[g] : xbv[g];
        mid[g].x = __shfl(X.x, lane ^ 32);
        mid[g].y = __shfl(X.y, lane ^ 32);
        mid[g].z = __shfl(X.z, lane ^ 32);
        mid[g].w = __shfl(X.w, lane ^ 32);
    }

    // ---- compute (R4/R5-validated shfl-halo FMA chain) ----
    f32x4 acc[G_];
#pragma unroll
    for (int g = 0; g < G_; ++g) acc[g] = (f32x4)(0.f);

#pragma unroll
    for (int a = 0; a < 3; ++a) {
        const int hh = ho + a - 1;
        if (hh < 0 || hh >= H_) continue;  // zero-pad rows (divergent at image edge)
        const f32x4 wa = wv[a * 3 + 0];
        const f32x4 wm = wv[a * 3 + 1];
        const f32x4 wc = wv[a * 3 + 2];
#pragma unroll
        for (int g = 0; g < G_; ++g) {
            const f32x4 xv = (a == 0) ? xa[g] : ((a == 1) ? mid[g] : xbv[g]);
            float xl = __shfl(xv.w, lane - 1);
            float xr = __shfl(xv.x, lane + 1);
            xl = (widx == 0) ? 0.f : xl;   // x[-1] pad
            xr = (widx == 23) ? 0.f : xr;  // x[96] pad
            acc[g].x = fmaf(xl,   wa.x, acc[g].x);
            acc[g].x = fmaf(xv.x, wm.x, acc[g].x);
            acc[g].x = fmaf(xv.y, wc.x, acc[g].x);
            acc[g].y = fmaf(xv.x, wa.y, acc[g].y);
            acc[g].y = fmaf(xv.y, wm.y, acc[g].y);
            acc[g].y = fmaf(xv.z, wc.y, acc[g].y);
            acc[g].z = fmaf(xv.y, wa.z, acc[g].z);
            acc[g].z = fmaf(xv.z, wm.z, acc[g].z);
            acc[g].z = fmaf(xv.w, wc.z, acc[g].z);
            acc[g].w = fmaf(xv.z, wa.w, acc[g].w);
            acc[g].w = fmaf(xv.w, wm.w, acc[g].w);
            acc[g].w = fmaf(xr,   wc.w, acc[g].w);
        }
    }

    // plain stores: L2 absorbs and drains lazily
    float* ob = out + (size_t)((n * C_ + cw) * PL_) + ho * W_ + w0;
#pragma unroll
    for (int g = 0; g < G_; ++g) {
        *reinterpret_cast<f32x4*>(ob + (size_t)(g * CW_) * PL_) = acc[g];
    }
}

extern "C" void kernel_launch(void* const* d_in, const int* in_sizes, int n_in,
                              void* d_out, int out_size, void* d_ws, size_t ws_size,
                              hipStream_t stream) {
    const float* x   = (const float*)d_in[0];
    const float* wgt = (const float*)d_in[1];
    float* out = (float*)d_out;

    constexpr int grid = N_ * CW_ * (H_ / 8);  // 3072 blocks x 256 threads
    SKA_kernel<<<grid, 256, 0, stream>>>(x, wgt, out);
}

// Round 15
// 41.636 us; speedup vs baseline: 1.0374x; 1.0374x over previous
//
#include <hip/hip_runtime.h>
#include <stdint.h>

// SKA: out[n, g*CW+cw, h, w] = sum_{a,b in 0..2} x[n, g*CW+cw, h+a-1, w+b-1] * w[n, cw, a*3+b, h, w]
// x: (8, 256, 96, 96) f32 ; w: (8, 32, 9, 96, 96) f32 ; out: (8, 256, 96, 96) f32
// Round 14: terminal revert to the Round-11 kernel (best measured: 41.5 us).
// Evidence R1/R2/R4/R7/R8/R11/R13 (7 structures, 41.5-54 us) shows the op is
// pinned at the cache-hierarchy service ceiling: ~311 MB compulsory traffic
// through the L2-miss path at ~7.5 TB/s aggregate (L3+HBM). No cross-block
// reuse exists to cut it. Structure: order-pinned asm load batch (one latency
// window/wave), g-outer DRAM clusters, plain stores, XCD-bijective swizzle.

#define N_  8
#define C_  256
#define H_  96
#define W_  96
#define CW_ 32
#define G_  8
#define PL_ (H_ * W_)  // 9216

typedef float f32x4 __attribute__((ext_vector_type(4)));

// order-pinned 16B global load (compiler cannot sink/reorder volatile asm)
#define GLD(dst, addr) \
    asm volatile("global_load_dwordx4 %0, %1, off" : "=v"(dst) : "v"(addr))

__global__ __launch_bounds__(256) void SKA_kernel(const float* __restrict__ x,
                                                  const float* __restrict__ wgt,
                                                  float* __restrict__ out) {
    const int tid   = threadIdx.x;
    const int widx  = tid & 31;   // 0..31, 24 active (w0 = 4*widx < 96)
    const int rowid = tid >> 5;   // 0..7
    const int lane  = tid & 63;

    // XCD-bijective swizzle: 3072 blocks = 8 XCDs x 384; each XCD owns one image n.
    const int b  = blockIdx.x;
    const int lb = (b & 7) * 384 + (b >> 3);
    const int ht = lb % 12;
    const int t1 = lb / 12;       // 0..255
    const int cw = t1 % CW_;
    const int n  = t1 / CW_;      // 0..7
    const int h  = ht * 8 + rowid;
    const int w0 = widx * 4;

    if (widx >= 24) return;

    // ---- 9 per-pixel kernel taps (issued first, oldest in VMEM queue) ----
    const float* wb = wgt + (size_t)(((n * CW_ + cw) * 9) * H_ + h) * W_ + w0;
    f32x4 wv[9];
#pragma unroll
    for (int k = 0; k < 9; ++k)
        wv[k] = *reinterpret_cast<const f32x4*>(wb + k * PL_);
    __builtin_amdgcn_sched_barrier(0);  // pin wv issue before the x batch

    // ---- 24 order-pinned x loads, g-outer / a-inner: per-group the 3 window
    // rows are 384B apart -> ~1.2KB contiguous DRAM cluster per group ----
    const float* xb = x + (size_t)((n * C_ + cw) * PL_) + w0;
    const int r0 = (h - 1 < 0) ? 0 : h - 1;        // clamped; OOB rows masked at compute
    const int r2 = (h + 1 >= H_) ? H_ - 1 : h + 1;
    const int rows[3] = {r0, h, r2};

    f32x4 xm[3][G_];
#pragma unroll
    for (int g = 0; g < G_; ++g) {
        const float* xg = xb + (size_t)(g * CW_) * PL_;
#pragma unroll
        for (int a = 0; a < 3; ++a) {
            GLD(xm[a][g], xg + rows[a] * W_);
        }
    }

    // single drain of the pinned loads; fence consumer hoisting (rule #18)
    asm volatile("s_waitcnt vmcnt(0)" ::: "memory");
    __builtin_amdgcn_sched_barrier(0);

    // ---- compute (R4/R5-validated shfl-halo FMA chain) ----
    f32x4 acc[G_];
#pragma unroll
    for (int g = 0; g < G_; ++g) acc[g] = (f32x4)(0.f);

#pragma unroll
    for (int a = 0; a < 3; ++a) {
        const int hh = h + a - 1;
        if (hh < 0 || hh >= H_) continue;  // zero-pad rows
        const f32x4 wa = wv[a * 3 + 0];
        const f32x4 wm = wv[a * 3 + 1];
        const f32x4 wc = wv[a * 3 + 2];
#pragma unroll
        for (int g = 0; g < G_; ++g) {
            const f32x4 xv = xm[a][g];
            float xl = __shfl(xv.w, lane - 1);
            float xr = __shfl(xv.x, lane + 1);
            xl = (widx == 0) ? 0.f : xl;   // x[-1] pad
            xr = (widx == 23) ? 0.f : xr;  // x[96] pad
            acc[g].x = fmaf(xl,   wa.x, acc[g].x);
            acc[g].x = fmaf(xv.x, wm.x, acc[g].x);
            acc[g].x = fmaf(xv.y, wc.x, acc[g].x);
            acc[g].y = fmaf(xv.x, wa.y, acc[g].y);
            acc[g].y = fmaf(xv.y, wm.y, acc[g].y);
            acc[g].y = fmaf(xv.z, wc.y, acc[g].y);
            acc[g].z = fmaf(xv.y, wa.z, acc[g].z);
            acc[g].z = fmaf(xv.z, wm.z, acc[g].z);
            acc[g].z = fmaf(xv.w, wc.z, acc[g].z);
            acc[g].w = fmaf(xv.z, wa.w, acc[g].w);
            acc[g].w = fmaf(xv.w, wm.w, acc[g].w);
            acc[g].w = fmaf(xr,   wc.w, acc[g].w);
        }
    }

    // plain stores: let L2 absorb and drain lazily
    float* ob = out + (size_t)((n * C_ + cw) * PL_) + h * W_ + w0;
#pragma unroll
    for (int g = 0; g < G_; ++g) {
        *reinterpret_cast<f32x4*>(ob + (size_t)(g * CW_) * PL_) = acc[g];
    }
}

extern "C" void kernel_launch(void* const* d_in, const int* in_sizes, int n_in,
                              void* d_out, int out_size, void* d_ws, size_t ws_size,
                              hipStream_t stream) {
    const float* x   = (const float*)d_in[0];
    const float* wgt = (const float*)d_in[1];
    float* out = (float*)d_out;

    constexpr int grid = N_ * CW_ * (H_ / 8);  // 3072 blocks x 256 threads
    SKA_kernel<<<grid, 256, 0, stream>>>(x, wgt, out);
}